// Round 14
// baseline (112.702 us; speedup 1.0000x reference)
//
#include <hip/hip_runtime.h>
#include <stdint.h>

#define Bb 2
#define Ss 2048
#define Dd 1024
#define Hh 16
#define HDd 64
// M = B*S = 4096

typedef float f32x4 __attribute__((ext_vector_type(4)));
typedef __bf16 bf16x8 __attribute__((ext_vector_type(8)));
typedef __bf16 bf16x2 __attribute__((ext_vector_type(2)));
typedef short s16x8 __attribute__((ext_vector_type(8)));

__device__ inline unsigned short f2bf(float f) {
  unsigned u = __builtin_bit_cast(unsigned, f);
  u += 0x7fffu + ((u >> 16) & 1u);
  return (unsigned short)(u >> 16);
}
__device__ inline float bf2f(unsigned short h) {
  unsigned u = ((unsigned)h) << 16;
  return __builtin_bit_cast(float, u);
}
// native-cast pair pack: compiler fuses to v_cvt_pk_bf16_f32 (RNE)
__device__ inline unsigned pkcvt(float a, float b) {
  bf16x2 v;
  v[0] = (__bf16)a;
  v[1] = (__bf16)b;
  return __builtin_bit_cast(unsigned, v);
}
// native v_exp_f32 (2^x); avoid OCML precise exp2 path
__device__ inline float ex2(float x) {
#if __has_builtin(__builtin_amdgcn_exp2f)
  return __builtin_amdgcn_exp2f(x);
#else
  float r;
  asm("v_exp_f32 %0, %1\n\ts_nop 1" : "=v"(r) : "v"(x));
  return r;
#endif
}
// XOR-swizzled short-index into a [64-row][64-short] LDS tile (attn).
__device__ inline int swz(int row, int soff) {
  return (row << 6) + ((((soff >> 3) ^ (row & 7)) << 3) | (soff & 7));
}

#define GLDS(dst, src)                                                        \
  __builtin_amdgcn_global_load_lds(                                           \
      (const __attribute__((address_space(1))) void*)(src),                   \
      (__attribute__((address_space(3))) void*)(dst), 16, 0, 0)

// ---------------- fused cast fp32 -> bf16 (x, w_qkv, w_dense) ----------------
__global__ void cast_all(const float* __restrict__ x, const float* __restrict__ wq,
                         const float* __restrict__ wd, unsigned short* __restrict__ dst) {
  int i = blockIdx.x * blockDim.x + threadIdx.x;  // float4 units
  float4 v;
  if (i < 1048576) v = ((const float4*)x)[i];
  else if (i < 1835008) v = ((const float4*)wq)[i - 1048576];
  else v = ((const float4*)wd)[i - 1835008];
  ushort4 o;
  o.x = f2bf(v.x); o.y = f2bf(v.y); o.z = f2bf(v.z); o.w = f2bf(v.w);
  ((ushort4*)dst)[i] = o;
}

// ---------------- GEMM 256x192, BK=64, 512 thr = 8 waves (2m x 4n) ----------
// r13 structure + SOFTWARE-PIPELINED fragment reads: each phase issues the
// NEXT phase's ds_reads (double reg sets af0/af1, bfr0/bfr1), so LDS latency
// hides under MFMA/barrier-wait. 2 barriers/K-tile. Ledger: prologue 8 issued,
// vmcnt(4); P1 vmcnt(2) (6 in flight, oldest4 = cur-kc1); P3 vmcnt(4)
// (8 in flight, oldest4 = nxt-kc0). Last tile: vmcnt(0) / no tail.
// MODE 0: fp32 out + bias.  MODE 2: fused QKV epilogue -> rope(q,k)->qkv bf16,
// v -> vt[b,h,d,s] (transpose), using cos/sin tables.
template <int MODE>
__global__ __launch_bounds__(512, 2) void gemm256(
    const unsigned short* __restrict__ A, const unsigned short* __restrict__ Bw,
    const float* __restrict__ bias, void* __restrict__ Cout,
    unsigned short* __restrict__ vtout,
    const float* __restrict__ fc, const float* __restrict__ fs,
    int M, int N, int K, int NT) {
  __shared__ __align__(16) unsigned short Asl[2][2][256 * 32];
  __shared__ __align__(16) unsigned short Bsl[2][2][256 * 32];
  const int tid = threadIdx.x;
  const int w = tid >> 6, l = tid & 63;
  const int lg = l >> 4, lr = l & 15;
  const int wm = w >> 2, wn = w & 3;
  // XCD-bijective swizzle (nwg % 8 == 0)
  int id = blockIdx.y * gridDim.x + blockIdx.x;
  const int nwg = gridDim.x * gridDim.y;
  id = (id & 7) * (nwg >> 3) + (id >> 3);
  const int bx = id % gridDim.x, by = id / gridDim.x;
  const int mbase = by * 256, nbase = bx * 192;

  const int r0 = w * 16 + (l >> 2);
  const int r1 = r0 + 128;
  const int sp = l & 3;
  const unsigned short* a0 = A + (size_t)(mbase + r0) * K + (sp ^ ((r0 >> 1) & 3)) * 8;
  const unsigned short* a1 = A + (size_t)(mbase + r1) * K + (sp ^ ((r1 >> 1) & 3)) * 8;
  const unsigned short* b0 = Bw + (size_t)(nbase + r0) * K + (sp ^ ((r0 >> 1) & 3)) * 8;
  const unsigned short* b1 = Bw + (size_t)(nbase + r1) * K + (sp ^ ((r1 >> 1) & 3)) * 8;
  const int d0 = w * 512 + l * 8;
  const int d1 = d0 + 4096;

  // fragment read helpers (swizzled)
#define RD_B(dst, buf, half)                                                  \
  _Pragma("unroll")                                                           \
  for (int ni = 0; ni < 3; ++ni) {                                            \
    int row = wn * 48 + ni * 16 + lr;                                         \
    dst[ni] = *(const bf16x8*)(&Bsl[buf][half][row * 32 +                     \
                  ((lg ^ ((row >> 1) & 3)) << 3)]);                           \
  }
#define RD_A(dst, buf, half, hh)                                              \
  _Pragma("unroll")                                                           \
  for (int j = 0; j < 4; ++j) {                                               \
    int row = wm * 128 + (j + (hh) * 4) * 16 + lr;                            \
    dst[j] = *(const bf16x8*)(&Asl[buf][half][row * 32 +                      \
                  ((lg ^ ((row >> 1) & 3)) << 3)]);                           \
  }
#define MFMA12(afv, bfv, off)                                                 \
  __builtin_amdgcn_s_setprio(1);                                              \
  _Pragma("unroll")                                                           \
  for (int j = 0; j < 4; ++j)                                                 \
    _Pragma("unroll")                                                         \
    for (int ni = 0; ni < 3; ++ni)                                            \
      acc[j + (off)][ni] = __builtin_amdgcn_mfma_f32_16x16x32_bf16(           \
          afv[j], bfv[ni], acc[j + (off)][ni], 0, 0, 0);                      \
  __builtin_amdgcn_s_setprio(0);

  // prologue: stage tile 0 (order B0 A0 B1 A1), wait kc0, read P0 frags
  GLDS(&Bsl[0][0][d0], b0);      GLDS(&Bsl[0][0][d1], b1);
  GLDS(&Asl[0][0][d0], a0);      GLDS(&Asl[0][0][d1], a1);
  GLDS(&Bsl[0][1][d0], b0 + 32); GLDS(&Bsl[0][1][d1], b1 + 32);
  GLDS(&Asl[0][1][d0], a0 + 32); GLDS(&Asl[0][1][d1], a1 + 32);
  asm volatile("s_waitcnt vmcnt(4)" ::: "memory");
  __builtin_amdgcn_s_barrier();
  asm volatile("" ::: "memory");

  bf16x8 bfr0[3], bfr1[3], af0[4], af1[4];
  RD_B(bfr0, 0, 0);
  RD_A(af0, 0, 0, 0);

  f32x4 acc[8][3] = {};
  for (int t = 0; t < NT; ++t) {
    const int cur = t & 1, nxt = cur ^ 1;
    const int kN = (t + 1) * 64;
    const bool pf = (t + 1 < NT);
    // ---------- P0: MFMA(af0,bfr0); prefetch-read A[cur][0] h1 ----------
    RD_A(af1, cur, 0, 1);
    if (pf) { GLDS(&Bsl[nxt][0][d0], b0 + kN); GLDS(&Bsl[nxt][0][d1], b1 + kN); }
    MFMA12(af0, bfr0, 0);
    // ---------- P1: wait cur-kc1; MFMA(af1,bfr0); read kc1 frags ----------
    if (pf) asm volatile("s_waitcnt vmcnt(2)" ::: "memory");
    else    asm volatile("s_waitcnt vmcnt(0)" ::: "memory");
    __builtin_amdgcn_s_barrier();
    asm volatile("" ::: "memory");
    RD_B(bfr1, cur, 1);
    RD_A(af0, cur, 1, 0);
    if (pf) { GLDS(&Asl[nxt][0][d0], a0 + kN); GLDS(&Asl[nxt][0][d1], a1 + kN); }
    MFMA12(af1, bfr0, 4);
    // ---------- P2: MFMA(af0,bfr1); prefetch-read A[cur][1] h1 ----------
    RD_A(af1, cur, 1, 1);
    if (pf) { GLDS(&Bsl[nxt][1][d0], b0 + kN + 32); GLDS(&Bsl[nxt][1][d1], b1 + kN + 32); }
    MFMA12(af0, bfr1, 0);
    // ---------- P3: MFMA(af1,bfr1); wait nxt-kc0; read next P0 frags ----------
    if (pf) { GLDS(&Asl[nxt][1][d0], a0 + kN + 32); GLDS(&Asl[nxt][1][d1], a1 + kN + 32); }
    MFMA12(af1, bfr1, 4);
    if (pf) {
      asm volatile("s_waitcnt vmcnt(4)" ::: "memory");
      __builtin_amdgcn_s_barrier();
      asm volatile("" ::: "memory");
      RD_B(bfr0, nxt, 0);
      RD_A(af0, nxt, 0, 0);
    }
  }
#undef RD_B
#undef RD_A
#undef MFMA12

  // ---------------- epilogue ----------------
#pragma unroll
  for (int mi = 0; mi < 8; ++mi)
#pragma unroll
    for (int ni = 0; ni < 3; ++ni) {
      int col = nbase + wn * 48 + ni * 16 + lr;
      float bi = bias[col];
      int row0 = mbase + wm * 128 + mi * 16 + lg * 4;
      float o4[4];
#pragma unroll
      for (int r = 0; r < 4; ++r) o4[r] = acc[mi][ni][r] + bi;
      if constexpr (MODE == 0) {
#pragma unroll
        for (int r = 0; r < 4; ++r)
          ((float*)Cout)[(size_t)(row0 + r) * N + col] = o4[r];
      } else {
        int sect = col >> 10;          // uniform per (mi,ni): col base mult of 16
        int d = col & 63;
        int srow0 = row0 & 2047;
        if (sect < 2) {
          // RoPE: pair partner is lane lr^1 (holds col^1)
          int p = d >> 1;
#pragma unroll
          for (int r = 0; r < 4; ++r) {
            float vp = __shfl_xor(o4[r], 1);
            float c = fc[(srow0 + r) * 32 + p];
            float s = fs[(srow0 + r) * 32 + p];
            float o = (d & 1) ? (vp * s + o4[r] * c) : (o4[r] * c - vp * s);
            ((unsigned short*)Cout)[(size_t)(row0 + r) * 3072 + col] = f2bf(o);
          }
        } else {
          // V -> vt[b,h,d,s], 4 consecutive s packed into one 8B store
          int bh = (row0 >> 11) * 16 + ((col >> 6) & 15);
          uint2 o;
          o.x = pkcvt(o4[0], o4[1]);
          o.y = pkcvt(o4[2], o4[3]);
          *(uint2*)&vtout[((size_t)(bh * 64 + d)) * 2048 + srow0] = o;
        }
      }
    }
}

// ---------------- GEMM: 128x128 m97 structure (GEMM2, fp32 out) ------
__global__ __launch_bounds__(256) void gemm_bt(
    const unsigned short* __restrict__ A, const unsigned short* __restrict__ Bw,
    const float* __restrict__ bias, float* __restrict__ Cout,
    int M, int N, int K) {
  __shared__ __align__(16) unsigned short As[128 * 32];
  __shared__ __align__(16) unsigned short Bs[128 * 32];
  const int tid = threadIdx.x;
  const int w = tid >> 6, l = tid & 63;
  const int lg = l >> 4, lr = l & 15;
  const int mbase = blockIdx.y * 128, nbase = blockIdx.x * 128;
  const int wr = w >> 1, wc = w & 1;
  f32x4 acc[4][4] = {};

  for (int k0 = 0; k0 < K; k0 += 32) {
#pragma unroll
    for (int r = 0; r < 2; ++r) {
      int c = r * 256 + w * 64 + l;
      int row = c >> 2, c8 = c & 3;
      GLDS(As + c * 8, A + (size_t)(mbase + row) * K + k0 + c8 * 8);
      GLDS(Bs + c * 8, Bw + (size_t)(nbase + row) * K + k0 + c8 * 8);
    }
    __syncthreads();
    bf16x8 af[4], bfr[4];
#pragma unroll
    for (int mi = 0; mi < 4; ++mi)
      af[mi] = *(const bf16x8*)(As + (wr * 64 + mi * 16 + lr) * 32 + lg * 8);
#pragma unroll
    for (int ni = 0; ni < 4; ++ni)
      bfr[ni] = *(const bf16x8*)(Bs + (wc * 64 + ni * 16 + lr) * 32 + lg * 8);
#pragma unroll
    for (int mi = 0; mi < 4; ++mi)
#pragma unroll
      for (int ni = 0; ni < 4; ++ni)
        acc[mi][ni] = __builtin_amdgcn_mfma_f32_16x16x32_bf16(
            af[mi], bfr[ni], acc[mi][ni], 0, 0, 0);
    __syncthreads();
  }

#pragma unroll
  for (int mi = 0; mi < 4; ++mi) {
#pragma unroll
    for (int ni = 0; ni < 4; ++ni) {
      int col = nbase + wc * 64 + ni * 16 + lr;
      float bi = bias[col];
#pragma unroll
      for (int r = 0; r < 4; ++r) {
        int row = mbase + wr * 64 + mi * 16 + lg * 4 + r;
        Cout[(size_t)row * N + col] = acc[mi][ni][r] + bi;
      }
    }
  }
}

// ---------------- Flash attention (causal), split-K swapped form ----------------
// Block = (bh, 64 q-rows), 8 waves = 4 q-groups (wq) x 2 k-slices (wk).
// Wave (wq,wk) streams k-tiles kt = 2j+wk with private (m,l,acc); merge at end
// via LDS. launch_bounds(512,4): VGPR budget 128 -> no spill.
__global__ __launch_bounds__(512, 4) void attn(
    const unsigned short* __restrict__ qkv, const unsigned short* __restrict__ vt,
    unsigned short* __restrict__ ctx) {
  __shared__ __align__(16) unsigned short Ks[2][64 * 64];
  __shared__ __align__(16) unsigned short Vs[2][64 * 64];
  __shared__ __align__(16) unsigned short Ps[8][16 * 64];
  int did = blockIdx.x;                  // 1024 blocks
  int x = did & 7, rest = did >> 3;      // XCD x owns bh 4x..4x+3
  int bh = x * 4 + (rest & 3);
  int qi = 31 - (rest >> 2);             // LPT: heavy q-tiles first
  int b = bh >> 4, h = bh & 15;
  int qbase = qi * 64;
  int tid = threadIdx.x;
  int w = tid >> 6, l = tid & 63;
  int lg = l >> 4, lr = l & 15;
  int wq = w & 3, wk = w >> 2;

  // Q fragments for q-rows qbase + wq*16 + lr, pre-scaled into log2 domain
  bf16x8 qb[2];
#pragma unroll
  for (int kc = 0; kc < 2; ++kc) {
    s16x8 qr = *(const s16x8*)(qkv +
        (size_t)(b * Ss + qbase + wq * 16 + lr) * 3072 + h * 64 + kc * 32 + lg * 8);
    bf16x8 qs;
#pragma unroll
    for (int e = 0; e < 8; ++e)
      qs[e] = (__bf16)(bf2f((unsigned short)qr[e]) * 0.18033688f);
    qb[kc] = qs;
  }

  // staging: thread covers tile-slot tt of the pair, row rr, shorts [sc,sc+16)
  int tt = tid >> 8, rr = (tid >> 2) & 63, sc = (tid & 3) * 16;
  const unsigned short* kp =
      qkv + ((size_t)(b * Ss) + rr) * 3072 + 1024 + h * 64 + sc;   // + tile*64*3072
  const unsigned short* vp = vt + ((size_t)bh * 64 + rr) * 2048 + sc;  // + tile*64

  int nkt = qi + 1;
  int nsup = (nkt + 1) >> 1;

  // prologue: stage pair 0 (tiles 0,1) straight to LDS
  if (tt < nkt) {
    const unsigned short* gk = kp + (size_t)tt * 64 * 3072;
    const unsigned short* gv = vp + tt * 64;
    *(s16x8*)&Ks[tt][swz(rr, sc)]     = *(const s16x8*)gk;
    *(s16x8*)&Ks[tt][swz(rr, sc + 8)] = *(const s16x8*)(gk + 8);
    *(s16x8*)&Vs[tt][swz(rr, sc)]     = *(const s16x8*)gv;
    *(s16x8*)&Vs[tt][swz(rr, sc + 8)] = *(const s16x8*)(gv + 8);
  }
  s16x8 rk0, rk1, rv0, rv1;
  if (2 + tt < nkt) {                    // prefetch pair 1 (tiles 2,3) into regs
    const unsigned short* gk = kp + (size_t)(2 + tt) * 64 * 3072;
    const unsigned short* gv = vp + (2 + tt) * 64;
    rk0 = *(const s16x8*)gk;  rk1 = *(const s16x8*)(gk + 8);
    rv0 = *(const s16x8*)gv;  rv1 = *(const s16x8*)(gv + 8);
  }
  __syncthreads();

  f32x4 acc[4] = {};          // ctx^T partial: acc[nd], rows d, cols q(=lr)
  float mrow = -1e30f, lsum = 0.f;

  for (int j = 0; j < nsup; ++j) {
    int kt = 2 * j + wk;
    if (kt < nkt) {
      // S^T = K Q^T (log2-scaled)
      f32x4 st[4] = {};
      __builtin_amdgcn_s_setprio(1);
#pragma unroll
      for (int kc = 0; kc < 2; ++kc) {
#pragma unroll
        for (int ni = 0; ni < 4; ++ni) {
          bf16x8 ka = *(const bf16x8*)&Ks[wk][swz(ni * 16 + lr, kc * 32 + lg * 8)];
          st[ni] = __builtin_amdgcn_mfma_f32_16x16x32_bf16(ka, qb[kc], st[ni], 0, 0, 0);
        }
      }
      __builtin_amdgcn_s_setprio(0);

      float tm = -1e30f;
      if (kt == qi) {               // diagonal tile: causal mask (in place)
        int rq = wq * 16 + lr;
#pragma unroll
        for (int ni = 0; ni < 4; ++ni)
#pragma unroll
          for (int r4 = 0; r4 < 4; ++r4) {
            float s = st[ni][r4];
            if (ni * 16 + lg * 4 + r4 > rq) s = -1e30f;
            st[ni][r4] = s;
            tm = fmaxf(tm, s);
          }
      } else {
#pragma unroll
        for (int ni = 0; ni < 4; ++ni)
#pragma unroll
          for (int r4 = 0; r4 < 4; ++r4) tm = fmaxf(tm, st[ni][r4]);
      }
      // defer-max: cross-lane reduce + rescale only when bound trips
      if (!__all(tm <= mrow + 8.0f)) {
        tm = fmaxf(tm, __shfl_xor(tm, 16));
        tm = fmaxf(tm, __shfl_xor(tm, 32));
        float mnew = fmaxf(mrow, tm);
        float alpha = ex2(mrow - mnew);
        lsum *= alpha;
#pragma unroll
        for (int nd = 0; nd < 4; ++nd)
#pragma unroll
          for (int r4 = 0; r4 < 4; ++r4) acc[nd][r4] *= alpha;
        mrow = mnew;
      }
      float sum = 0.f;
#pragma unroll
      for (int ni = 0; ni < 4; ++ni)
#pragma unroll
        for (int r4 = 0; r4 < 4; ++r4) {
          float pe = ex2(st[ni][r4] - mrow);
          st[ni][r4] = pe;
          sum += pe;
        }
      lsum += sum;                  // per-lane partial
      // P[q=lr][k] -> per-wave LDS (swizzled)
#pragma unroll
      for (int ni = 0; ni < 4; ++ni) {
        uint2 wv;
        wv.x = pkcvt(st[ni][0], st[ni][1]);
        wv.y = pkcvt(st[ni][2], st[ni][3]);
        *(uint2*)&Ps[w][swz(lr, ni * 16 + lg * 4)] = wv;
      }
      // ctx^T += V^T P^T
      __builtin_amdgcn_s_setprio(1);
#pragma unroll
      for (int kc = 0; kc < 2; ++kc) {
        bf16x8 pbf = *(const bf16x8*)&Ps[w][swz(lr, kc * 32 + lg * 8)];
#pragma unroll
        for (int nd = 0; nd < 4; ++nd) {
          bf16x8 va = *(const bf16x8*)&Vs[wk][swz(nd * 16 + lr, kc * 32 + lg * 8)];
          acc[nd] = __builtin_amdgcn_mfma_f32_16x16x32_bf16(va, pbf, acc[nd], 0, 0, 0);
        }
      }
      __builtin_amdgcn_s_setprio(0);
    }

    if (j + 1 < nsup) {
      __syncthreads();              // all waves done with pair j
      int tw = 2 * (j + 1) + tt;
      if (tw < nkt) {
        *(s16x8*)&Ks[tt][swz(rr, sc)]     = rk0;
        *(s16x8*)&Ks[tt][swz(rr, sc + 8)] = rk1;
        *(s16x8*)&Vs[tt][swz(rr, sc)]     = rv0;
        *(s16x8*)&Vs[tt][swz(rr, sc + 8)] = rv1;
      }
      int tn = 2 * (j + 2) + tt;
      if (tn < nkt) {               // issue loads for pair j+2
        const unsigned short* gk = kp + (size_t)tn * 64 * 3072;
        const unsigned short* gv = vp + tn * 64;
        rk0 = *(const s16x8*)gk;  rk1 = *(const s16x8*)(gk + 8);
        rv0 = *(const s16x8*)gv;  rv1 = *(const s16x8*)(gv + 8);
      }
      __syncthreads();              // writes visible
    }
  }

  // ---- combine the two k-slices of each q-group ----
  lsum += __shfl_xor(lsum, 16);     // full row sum for this slice
  lsum += __shfl_xor(lsum, 32);
  __syncthreads();                  // done reading K/V tiles; reuse as scratch
  float* accS = (float*)Vs;         // [4][64][16] fp32 = 16KB
  float* mlS  = (float*)Ks;         // [4][64][2]
  if (wk == 1) {
    float* as = accS + (wq * 64 + l) * 16;
#pragma unroll
    for (int nd = 0; nd < 4; ++nd) *(f32x4*)(as + nd * 4) = acc[nd];
    mlS[(wq * 64 + l) * 2 + 0] = mrow;
    mlS[(wq * 64 + l) * 2 + 1] = lsum;
  }
  __syncthreads();
  if (wk == 0) {
    const float* as = accS + (wq * 64 + l) * 16;
    float m1 = mlS[(wq * 64 + l) * 2 + 0];
    float l1 = mlS[(wq * 64 + l) * 2 + 1];
    float M  = fmaxf(mrow, m1);
    float s0 = ex2(mrow - M), s1 = ex2(m1 - M);
    float inv = 1.0f / (lsum * s0 + l1 * s1);
    float f0 = s0 * inv, f1 = s1 * inv;
    int qg = qbase + wq * 16 + lr;
#pragma unroll
    for (int nd = 0; nd < 4; ++nd) {
      f32x4 a1 = *(const f32x4*)(as + nd * 4);
      uint2 o;
      o.x = pkcvt(acc[nd][0] * f0 + a1[0] * f1, acc[nd][1] * f0 + a1[1] * f1);
      o.y = pkcvt(acc[nd][2] * f0 + a1[2] * f1, acc[nd][3] * f0 + a1[3] * f1);
      *(uint2*)&ctx[((size_t)(b * Ss) + qg) * 1024 + h * 64 + nd * 16 + lg * 4] = o;
    }
  }
}

extern "C" void kernel_launch(void* const* d_in, const int* in_sizes, int n_in,
                              void* d_out, int out_size, void* d_ws, size_t ws_size,
                              hipStream_t stream) {
  const float* x       = (const float*)d_in[0];
  const float* w_qkv   = (const float*)d_in[1];
  const float* b_qkv   = (const float*)d_in[2];
  const float* w_dense = (const float*)d_in[3];
  const float* b_dense = (const float*)d_in[4];
  const float* fc      = (const float*)d_in[5];
  const float* fs      = (const float*)d_in[6];
  float* out = (float*)d_out;

  char* ws = (char*)d_ws;
  unsigned short* xb    = (unsigned short*)(ws);                        // 8 MB
  unsigned short* wqkvb = (unsigned short*)(ws + (8ull  << 20));        // 6 MB
  unsigned short* wdb   = (unsigned short*)(ws + (14ull << 20));        // 2 MB
  unsigned short* qkvb  = (unsigned short*)(ws + (16ull << 20));        // 24 MB
  unsigned short* vt    = (unsigned short*)(ws + (40ull << 20));        // 8 MB

  cast_all<<<8192, 256, 0, stream>>>(x, w_qkv, w_dense, xb);

  // GEMM1 fused (256x192 tiles -> 256 blocks = 1/CU):
  // rope(q,k) -> qkvb ; v -> vt (transposed)
  gemm256<2><<<dim3(16, 16), 512, 0, stream>>>(xb, wqkvb, b_qkv, qkvb, vt,
                                               fc, fs, 4096, 3072, 1024, 16);
  attn<<<1024, 512, 0, stream>>>(qkvb, vt, xb /* ctx reuse */);
  gemm_bt<<<dim3(8, 32), 256, 0, stream>>>(xb, wdb, b_dense, out,
                                           4096, 1024, 1024);
}

// Round 15
// 108.061 us; speedup vs baseline: 1.0429x; 1.0429x over previous
//
#include <hip/hip_runtime.h>
#include <stdint.h>

#define Bb 2
#define Ss 2048
#define Dd 1024
#define Hh 16
#define HDd 64
// M = B*S = 4096

typedef float f32x4 __attribute__((ext_vector_type(4)));
typedef __bf16 bf16x8 __attribute__((ext_vector_type(8)));
typedef __bf16 bf16x2 __attribute__((ext_vector_type(2)));
typedef short s16x8 __attribute__((ext_vector_type(8)));

__device__ inline unsigned short f2bf(float f) {
  unsigned u = __builtin_bit_cast(unsigned, f);
  u += 0x7fffu + ((u >> 16) & 1u);
  return (unsigned short)(u >> 16);
}
__device__ inline float bf2f(unsigned short h) {
  unsigned u = ((unsigned)h) << 16;
  return __builtin_bit_cast(float, u);
}
// native-cast pair pack: compiler fuses to v_cvt_pk_bf16_f32 (RNE)
__device__ inline unsigned pkcvt(float a, float b) {
  bf16x2 v;
  v[0] = (__bf16)a;
  v[1] = (__bf16)b;
  return __builtin_bit_cast(unsigned, v);
}
// native v_exp_f32 (2^x); avoid OCML precise exp2 path
__device__ inline float ex2(float x) {
#if __has_builtin(__builtin_amdgcn_exp2f)
  return __builtin_amdgcn_exp2f(x);
#else
  float r;
  asm("v_exp_f32 %0, %1\n\ts_nop 1" : "=v"(r) : "v"(x));
  return r;
#endif
}
// XOR-swizzled short-index into a [64-row][64-short] LDS tile (attn).
__device__ inline int swz(int row, int soff) {
  return (row << 6) + ((((soff >> 3) ^ (row & 7)) << 3) | (soff & 7));
}

#define GLDS(dst, src)                                                        \
  __builtin_amdgcn_global_load_lds(                                           \
      (const __attribute__((address_space(1))) void*)(src),                   \
      (__attribute__((address_space(3))) void*)(dst), 16, 0, 0)

// ---------------- fused cast fp32 -> bf16 (x, w_qkv, w_dense) ----------------
__global__ void cast_all(const float* __restrict__ x, const float* __restrict__ wq,
                         const float* __restrict__ wd, unsigned short* __restrict__ dst) {
  int i = blockIdx.x * blockDim.x + threadIdx.x;  // float4 units
  float4 v;
  if (i < 1048576) v = ((const float4*)x)[i];
  else if (i < 1835008) v = ((const float4*)wq)[i - 1048576];
  else v = ((const float4*)wd)[i - 1835008];
  ushort4 o;
  o.x = f2bf(v.x); o.y = f2bf(v.y); o.z = f2bf(v.z); o.w = f2bf(v.w);
  ((ushort4*)dst)[i] = o;
}

// ---------------- GEMM1 fused: 128x192 tile, BK=64, 512 thr = 8 waves -------
// 512 blocks x 80KB LDS = 2 blocks/CU (4 waves/SIMD): cross-block TLP hides
// load latency (m114/m97 lesson; r13/r14's 1-block/CU phase machinery could
// not). One barrier per K-tile: STAGE(next buf) -> compute(cur) -> sync
// (sync's vmcnt-drain lands the next-tile loads under this tile's compute).
// Swizzled LDS (slot ^ (row>>1)&3, 0 conflicts), GLDS 5 chunks/thread.
// Fused epilogue: rope(q,k) -> qkv bf16; v -> vt[b,h,d,s] (transpose).
__global__ __launch_bounds__(512, 2) void gemm_qkv(
    const unsigned short* __restrict__ A, const unsigned short* __restrict__ Bw,
    const float* __restrict__ bias, unsigned short* __restrict__ qkvout,
    unsigned short* __restrict__ vtout,
    const float* __restrict__ fc, const float* __restrict__ fs) {
  const int K = 1024, NT = 16;
  __shared__ __align__(16) unsigned short Ah[2][2][128 * 32];  // 32 KB
  __shared__ __align__(16) unsigned short Bh[2][2][192 * 32];  // 48 KB
  const int tid = threadIdx.x;
  const int w = tid >> 6, l = tid & 63;
  const int lg = l >> 4, lr = l & 15;
  const int wm = w >> 2, wn = w & 3;          // 2m x 4n wave grid
  // XCD-bijective swizzle (nwg = 512, % 8 == 0)
  int id = blockIdx.y * gridDim.x + blockIdx.x;
  const int nwg = gridDim.x * gridDim.y;
  id = (id & 7) * (nwg >> 3) + (id >> 3);
  const int bx = id % gridDim.x, by = id / gridDim.x;
  const int mbase = by * 128, nbase = bx * 192;

  // staging sources (5 chunks/thread; LDS dst flat-linear in chunk id):
  // A chunks {t, 512+t}: half = c>=512, row = (c&511)>>2, slot = c&3
  // B chunks {t, 512+t, 1024+t}: half = c>=768, cw = c-half*768, row = cw>>2
  const unsigned short *as0, *bs0, *bs1, *bs2;
  {
    int r_ = tid >> 2, s_ = (tid & 3) ^ ((r_ >> 1) & 3);
    as0 = A + (size_t)(mbase + r_) * K + s_ * 8;           // half1 = +32
    bs0 = Bw + (size_t)(nbase + r_) * K + s_ * 8;          // cb=t: rows 0..127, h0
    int cb2 = 512 + tid;
    int h2 = cb2 >= 768;
    int cw2 = cb2 - h2 * 768;
    int r2 = cw2 >> 2, s2 = (cw2 & 3) ^ ((r2 >> 1) & 3);
    bs1 = Bw + (size_t)(nbase + r2) * K + h2 * 32 + s2 * 8;
    int cw3 = 256 + tid;                                   // cb=1024+t: h1
    int r3 = cw3 >> 2, s3 = (cw3 & 3) ^ ((r3 >> 1) & 3);
    bs2 = Bw + (size_t)(nbase + r3) * K + 32 + s3 * 8;
  }
#define STAGE(buf, k0)                                                        \
  GLDS(&Ah[buf][0][0] + tid * 8, as0 + (k0));                                 \
  GLDS(&Ah[buf][0][0] + 4096 + tid * 8, as0 + 32 + (k0));                     \
  GLDS(&Bh[buf][0][0] + tid * 8, bs0 + (k0));                                 \
  GLDS(&Bh[buf][0][0] + (512 + tid) * 8, bs1 + (k0));                         \
  GLDS(&Bh[buf][0][0] + (1024 + tid) * 8, bs2 + (k0));

  STAGE(0, 0);
  __syncthreads();

  f32x4 acc[4][3] = {};
  for (int t = 0; t < NT; ++t) {
    const int cur = t & 1;
    if (t + 1 < NT) { STAGE(cur ^ 1, (t + 1) * 64); }
#pragma unroll
    for (int h = 0; h < 2; ++h) {
      bf16x8 bfr[3], af[4];
#pragma unroll
      for (int ni = 0; ni < 3; ++ni) {
        int row = wn * 48 + ni * 16 + lr;
        bfr[ni] = *(const bf16x8*)(&Bh[cur][h][row * 32 + ((lg ^ ((row >> 1) & 3)) << 3)]);
      }
#pragma unroll
      for (int j = 0; j < 4; ++j) {
        int row = wm * 64 + j * 16 + lr;
        af[j] = *(const bf16x8*)(&Ah[cur][h][row * 32 + ((lg ^ ((row >> 1) & 3)) << 3)]);
      }
      __builtin_amdgcn_s_setprio(1);
#pragma unroll
      for (int j = 0; j < 4; ++j)
#pragma unroll
        for (int ni = 0; ni < 3; ++ni)
          acc[j][ni] = __builtin_amdgcn_mfma_f32_16x16x32_bf16(
              af[j], bfr[ni], acc[j][ni], 0, 0, 0);
      __builtin_amdgcn_s_setprio(0);
    }
    __syncthreads();   // drains next-tile GLDS; fences cur-buf reads
  }
#undef STAGE

  // ---------------- fused epilogue ----------------
#pragma unroll
  for (int mi = 0; mi < 4; ++mi)
#pragma unroll
    for (int ni = 0; ni < 3; ++ni) {
      int col = nbase + wn * 48 + ni * 16 + lr;
      float bi = bias[col];
      int row0 = mbase + wm * 64 + mi * 16 + lg * 4;
      float o4[4];
#pragma unroll
      for (int r = 0; r < 4; ++r) o4[r] = acc[mi][ni][r] + bi;
      int sect = col >> 10;          // uniform per (mi,ni): col base mult of 16
      int d = col & 63;
      int srow0 = row0 & 2047;
      if (sect < 2) {
        // RoPE: pair partner is lane lr^1 (holds col^1)
        int p = d >> 1;
#pragma unroll
        for (int r = 0; r < 4; ++r) {
          float vp = __shfl_xor(o4[r], 1);
          float c = fc[(srow0 + r) * 32 + p];
          float s = fs[(srow0 + r) * 32 + p];
          float o = (d & 1) ? (vp * s + o4[r] * c) : (o4[r] * c - vp * s);
          qkvout[(size_t)(row0 + r) * 3072 + col] = f2bf(o);
        }
      } else {
        // V -> vt[b,h,d,s], 4 consecutive s packed into one 8B store
        int bh = (row0 >> 11) * 16 + ((col >> 6) & 15);
        uint2 o;
        o.x = pkcvt(o4[0], o4[1]);
        o.y = pkcvt(o4[2], o4[3]);
        *(uint2*)&vtout[((size_t)(bh * 64 + d)) * 2048 + srow0] = o;
      }
    }
}

// ---------------- GEMM: 128x128 m97 structure (GEMM2, fp32 out) ------
__global__ __launch_bounds__(256) void gemm_bt(
    const unsigned short* __restrict__ A, const unsigned short* __restrict__ Bw,
    const float* __restrict__ bias, float* __restrict__ Cout,
    int M, int N, int K) {
  __shared__ __align__(16) unsigned short As[128 * 32];
  __shared__ __align__(16) unsigned short Bs[128 * 32];
  const int tid = threadIdx.x;
  const int w = tid >> 6, l = tid & 63;
  const int lg = l >> 4, lr = l & 15;
  const int mbase = blockIdx.y * 128, nbase = blockIdx.x * 128;
  const int wr = w >> 1, wc = w & 1;
  f32x4 acc[4][4] = {};

  for (int k0 = 0; k0 < K; k0 += 32) {
#pragma unroll
    for (int r = 0; r < 2; ++r) {
      int c = r * 256 + w * 64 + l;
      int row = c >> 2, c8 = c & 3;
      GLDS(As + c * 8, A + (size_t)(mbase + row) * K + k0 + c8 * 8);
      GLDS(Bs + c * 8, Bw + (size_t)(nbase + row) * K + k0 + c8 * 8);
    }
    __syncthreads();
    bf16x8 af[4], bfr[4];
#pragma unroll
    for (int mi = 0; mi < 4; ++mi)
      af[mi] = *(const bf16x8*)(As + (wr * 64 + mi * 16 + lr) * 32 + lg * 8);
#pragma unroll
    for (int ni = 0; ni < 4; ++ni)
      bfr[ni] = *(const bf16x8*)(Bs + (wc * 64 + ni * 16 + lr) * 32 + lg * 8);
#pragma unroll
    for (int mi = 0; mi < 4; ++mi)
#pragma unroll
      for (int ni = 0; ni < 4; ++ni)
        acc[mi][ni] = __builtin_amdgcn_mfma_f32_16x16x32_bf16(
            af[mi], bfr[ni], acc[mi][ni], 0, 0, 0);
    __syncthreads();
  }

#pragma unroll
  for (int mi = 0; mi < 4; ++mi) {
#pragma unroll
    for (int ni = 0; ni < 4; ++ni) {
      int col = nbase + wc * 64 + ni * 16 + lr;
      float bi = bias[col];
#pragma unroll
      for (int r = 0; r < 4; ++r) {
        int row = mbase + wr * 64 + mi * 16 + lg * 4 + r;
        Cout[(size_t)row * N + col] = acc[mi][ni][r] + bi;
      }
    }
  }
}

// ---------------- Flash attention (causal), split-K swapped form ----------------
// Block = (bh, 64 q-rows), 8 waves = 4 q-groups (wq) x 2 k-slices (wk).
// Wave (wq,wk) streams k-tiles kt = 2j+wk with private (m,l,acc); merge at end
// via LDS. launch_bounds(512,4): VGPR budget 128 -> no spill.
__global__ __launch_bounds__(512, 4) void attn(
    const unsigned short* __restrict__ qkv, const unsigned short* __restrict__ vt,
    unsigned short* __restrict__ ctx) {
  __shared__ __align__(16) unsigned short Ks[2][64 * 64];
  __shared__ __align__(16) unsigned short Vs[2][64 * 64];
  __shared__ __align__(16) unsigned short Ps[8][16 * 64];
  int did = blockIdx.x;                  // 1024 blocks
  int x = did & 7, rest = did >> 3;      // XCD x owns bh 4x..4x+3
  int bh = x * 4 + (rest & 3);
  int qi = 31 - (rest >> 2);             // LPT: heavy q-tiles first
  int b = bh >> 4, h = bh & 15;
  int qbase = qi * 64;
  int tid = threadIdx.x;
  int w = tid >> 6, l = tid & 63;
  int lg = l >> 4, lr = l & 15;
  int wq = w & 3, wk = w >> 2;

  // Q fragments for q-rows qbase + wq*16 + lr, pre-scaled into log2 domain
  bf16x8 qb[2];
#pragma unroll
  for (int kc = 0; kc < 2; ++kc) {
    s16x8 qr = *(const s16x8*)(qkv +
        (size_t)(b * Ss + qbase + wq * 16 + lr) * 3072 + h * 64 + kc * 32 + lg * 8);
    bf16x8 qs;
#pragma unroll
    for (int e = 0; e < 8; ++e)
      qs[e] = (__bf16)(bf2f((unsigned short)qr[e]) * 0.18033688f);
    qb[kc] = qs;
  }

  // staging: thread covers tile-slot tt of the pair, row rr, shorts [sc,sc+16)
  int tt = tid >> 8, rr = (tid >> 2) & 63, sc = (tid & 3) * 16;
  const unsigned short* kp =
      qkv + ((size_t)(b * Ss) + rr) * 3072 + 1024 + h * 64 + sc;   // + tile*64*3072
  const unsigned short* vp = vt + ((size_t)bh * 64 + rr) * 2048 + sc;  // + tile*64

  int nkt = qi + 1;
  int nsup = (nkt + 1) >> 1;

  // prologue: stage pair 0 (tiles 0,1) straight to LDS
  if (tt < nkt) {
    const unsigned short* gk = kp + (size_t)tt * 64 * 3072;
    const unsigned short* gv = vp + tt * 64;
    *(s16x8*)&Ks[tt][swz(rr, sc)]     = *(const s16x8*)gk;
    *(s16x8*)&Ks[tt][swz(rr, sc + 8)] = *(const s16x8*)(gk + 8);
    *(s16x8*)&Vs[tt][swz(rr, sc)]     = *(const s16x8*)gv;
    *(s16x8*)&Vs[tt][swz(rr, sc + 8)] = *(const s16x8*)(gv + 8);
  }
  s16x8 rk0, rk1, rv0, rv1;
  if (2 + tt < nkt) {                    // prefetch pair 1 (tiles 2,3) into regs
    const unsigned short* gk = kp + (size_t)(2 + tt) * 64 * 3072;
    const unsigned short* gv = vp + (2 + tt) * 64;
    rk0 = *(const s16x8*)gk;  rk1 = *(const s16x8*)(gk + 8);
    rv0 = *(const s16x8*)gv;  rv1 = *(const s16x8*)(gv + 8);
  }
  __syncthreads();

  f32x4 acc[4] = {};          // ctx^T partial: acc[nd], rows d, cols q(=lr)
  float mrow = -1e30f, lsum = 0.f;

  for (int j = 0; j < nsup; ++j) {
    int kt = 2 * j + wk;
    if (kt < nkt) {
      // S^T = K Q^T (log2-scaled)
      f32x4 st[4] = {};
      __builtin_amdgcn_s_setprio(1);
#pragma unroll
      for (int kc = 0; kc < 2; ++kc) {
#pragma unroll
        for (int ni = 0; ni < 4; ++ni) {
          bf16x8 ka = *(const bf16x8*)&Ks[wk][swz(ni * 16 + lr, kc * 32 + lg * 8)];
          st[ni] = __builtin_amdgcn_mfma_f32_16x16x32_bf16(ka, qb[kc], st[ni], 0, 0, 0);
        }
      }
      __builtin_amdgcn_s_setprio(0);

      float tm = -1e30f;
      if (kt == qi) {               // diagonal tile: causal mask (in place)
        int rq = wq * 16 + lr;
#pragma unroll
        for (int ni = 0; ni < 4; ++ni)
#pragma unroll
          for (int r4 = 0; r4 < 4; ++r4) {
            float s = st[ni][r4];
            if (ni * 16 + lg * 4 + r4 > rq) s = -1e30f;
            st[ni][r4] = s;
            tm = fmaxf(tm, s);
          }
      } else {
#pragma unroll
        for (int ni = 0; ni < 4; ++ni)
#pragma unroll
          for (int r4 = 0; r4 < 4; ++r4) tm = fmaxf(tm, st[ni][r4]);
      }
      // defer-max: cross-lane reduce + rescale only when bound trips
      if (!__all(tm <= mrow + 8.0f)) {
        tm = fmaxf(tm, __shfl_xor(tm, 16));
        tm = fmaxf(tm, __shfl_xor(tm, 32));
        float mnew = fmaxf(mrow, tm);
        float alpha = ex2(mrow - mnew);
        lsum *= alpha;
#pragma unroll
        for (int nd = 0; nd < 4; ++nd)
#pragma unroll
          for (int r4 = 0; r4 < 4; ++r4) acc[nd][r4] *= alpha;
        mrow = mnew;
      }
      float sum = 0.f;
#pragma unroll
      for (int ni = 0; ni < 4; ++ni)
#pragma unroll
        for (int r4 = 0; r4 < 4; ++r4) {
          float pe = ex2(st[ni][r4] - mrow);
          st[ni][r4] = pe;
          sum += pe;
        }
      lsum += sum;                  // per-lane partial
      // P[q=lr][k] -> per-wave LDS (swizzled)
#pragma unroll
      for (int ni = 0; ni < 4; ++ni) {
        uint2 wv;
        wv.x = pkcvt(st[ni][0], st[ni][1]);
        wv.y = pkcvt(st[ni][2], st[ni][3]);
        *(uint2*)&Ps[w][swz(lr, ni * 16 + lg * 4)] = wv;
      }
      // ctx^T += V^T P^T
      __builtin_amdgcn_s_setprio(1);
#pragma unroll
      for (int kc = 0; kc < 2; ++kc) {
        bf16x8 pbf = *(const bf16x8*)&Ps[w][swz(lr, kc * 32 + lg * 8)];
#pragma unroll
        for (int nd = 0; nd < 4; ++nd) {
          bf16x8 va = *(const bf16x8*)&Vs[wk][swz(nd * 16 + lr, kc * 32 + lg * 8)];
          acc[nd] = __builtin_amdgcn_mfma_f32_16x16x32_bf16(va, pbf, acc[nd], 0, 0, 0);
        }
      }
      __builtin_amdgcn_s_setprio(0);
    }

    if (j + 1 < nsup) {
      __syncthreads();              // all waves done with pair j
      int tw = 2 * (j + 1) + tt;
      if (tw < nkt) {
        *(s16x8*)&Ks[tt][swz(rr, sc)]     = rk0;
        *(s16x8*)&Ks[tt][swz(rr, sc + 8)] = rk1;
        *(s16x8*)&Vs[tt][swz(rr, sc)]     = rv0;
        *(s16x8*)&Vs[tt][swz(rr, sc + 8)] = rv1;
      }
      int tn = 2 * (j + 2) + tt;
      if (tn < nkt) {               // issue loads for pair j+2
        const unsigned short* gk = kp + (size_t)tn * 64 * 3072;
        const unsigned short* gv = vp + tn * 64;
        rk0 = *(const s16x8*)gk;  rk1 = *(const s16x8*)(gk + 8);
        rv0 = *(const s16x8*)gv;  rv1 = *(const s16x8*)(gv + 8);
      }
      __syncthreads();              // writes visible
    }
  }

  // ---- combine the two k-slices of each q-group ----
  lsum += __shfl_xor(lsum, 16);     // full row sum for this slice
  lsum += __shfl_xor(lsum, 32);
  __syncthreads();                  // done reading K/V tiles; reuse as scratch
  float* accS = (float*)Vs;         // [4][64][16] fp32 = 16KB
  float* mlS  = (float*)Ks;         // [4][64][2]
  if (wk == 1) {
    float* as = accS + (wq * 64 + l) * 16;
#pragma unroll
    for (int nd = 0; nd < 4; ++nd) *(f32x4*)(as + nd * 4) = acc[nd];
    mlS[(wq * 64 + l) * 2 + 0] = mrow;
    mlS[(wq * 64 + l) * 2 + 1] = lsum;
  }
  __syncthreads();
  if (wk == 0) {
    const float* as = accS + (wq * 64 + l) * 16;
    float m1 = mlS[(wq * 64 + l) * 2 + 0];
    float l1 = mlS[(wq * 64 + l) * 2 + 1];
    float M  = fmaxf(mrow, m1);
    float s0 = ex2(mrow - M), s1 = ex2(m1 - M);
    float inv = 1.0f / (lsum * s0 + l1 * s1);
    float f0 = s0 * inv, f1 = s1 * inv;
    int qg = qbase + wq * 16 + lr;
#pragma unroll
    for (int nd = 0; nd < 4; ++nd) {
      f32x4 a1 = *(const f32x4*)(as + nd * 4);
      uint2 o;
      o.x = pkcvt(acc[nd][0] * f0 + a1[0] * f1, acc[nd][1] * f0 + a1[1] * f1);
      o.y = pkcvt(acc[nd][2] * f0 + a1[2] * f1, acc[nd][3] * f0 + a1[3] * f1);
      *(uint2*)&ctx[((size_t)(b * Ss) + qg) * 1024 + h * 64 + nd * 16 + lg * 4] = o;
    }
  }
}

extern "C" void kernel_launch(void* const* d_in, const int* in_sizes, int n_in,
                              void* d_out, int out_size, void* d_ws, size_t ws_size,
                              hipStream_t stream) {
  const float* x       = (const float*)d_in[0];
  const float* w_qkv   = (const float*)d_in[1];
  const float* b_qkv   = (const float*)d_in[2];
  const float* w_dense = (const float*)d_in[3];
  const float* b_dense = (const float*)d_in[4];
  const float* fc      = (const float*)d_in[5];
  const float* fs      = (const float*)d_in[6];
  float* out = (float*)d_out;

  char* ws = (char*)d_ws;
  unsigned short* xb    = (unsigned short*)(ws);                        // 8 MB
  unsigned short* wqkvb = (unsigned short*)(ws + (8ull  << 20));        // 6 MB
  unsigned short* wdb   = (unsigned short*)(ws + (14ull << 20));        // 2 MB
  unsigned short* qkvb  = (unsigned short*)(ws + (16ull << 20));        // 24 MB
  unsigned short* vt    = (unsigned short*)(ws + (40ull << 20));        // 8 MB

  cast_all<<<8192, 256, 0, stream>>>(x, w_qkv, w_dense, xb);

  // GEMM1 fused (128x192 tiles -> 512 blocks = 2/CU):
  // rope(q,k) -> qkvb ; v -> vt (transposed)
  gemm_qkv<<<dim3(16, 32), 512, 0, stream>>>(xb, wqkvb, b_qkv, qkvb, vt, fc, fs);
  attn<<<1024, 512, 0, stream>>>(qkvb, vt, xb /* ctx reuse */);
  gemm_bt<<<dim3(8, 32), 256, 0, stream>>>(xb, wdb, b_dense, out,
                                           4096, 1024, 1024);
}

// Round 16
// 104.542 us; speedup vs baseline: 1.0781x; 1.0337x over previous
//
#include <hip/hip_runtime.h>
#include <stdint.h>

#define Bb 2
#define Ss 2048
#define Dd 1024
#define Hh 16
#define HDd 64
// M = B*S = 4096

typedef float f32x4 __attribute__((ext_vector_type(4)));
typedef __bf16 bf16x8 __attribute__((ext_vector_type(8)));
typedef __bf16 bf16x2 __attribute__((ext_vector_type(2)));
typedef short s16x8 __attribute__((ext_vector_type(8)));

__device__ inline unsigned short f2bf(float f) {
  unsigned u = __builtin_bit_cast(unsigned, f);
  u += 0x7fffu + ((u >> 16) & 1u);
  return (unsigned short)(u >> 16);
}
__device__ inline float bf2f(unsigned short h) {
  unsigned u = ((unsigned)h) << 16;
  return __builtin_bit_cast(float, u);
}
// native-cast pair pack: compiler fuses to v_cvt_pk_bf16_f32 (RNE)
__device__ inline unsigned pkcvt(float a, float b) {
  bf16x2 v;
  v[0] = (__bf16)a;
  v[1] = (__bf16)b;
  return __builtin_bit_cast(unsigned, v);
}
// native v_exp_f32 (2^x); avoid OCML precise exp2 path
__device__ inline float ex2(float x) {
#if __has_builtin(__builtin_amdgcn_exp2f)
  return __builtin_amdgcn_exp2f(x);
#else
  float r;
  asm("v_exp_f32 %0, %1\n\ts_nop 1" : "=v"(r) : "v"(x));
  return r;
#endif
}
// XOR-swizzled short-index into a [rows][64-short] LDS tile (attn).
__device__ inline int swz(int row, int soff) {
  return (row << 6) + ((((soff >> 3) ^ (row & 7)) << 3) | (soff & 7));
}

#define GLDS(dst, src)                                                        \
  __builtin_amdgcn_global_load_lds(                                           \
      (const __attribute__((address_space(1))) void*)(src),                   \
      (__attribute__((address_space(3))) void*)(dst), 16, 0, 0)

// ---------------- fused cast fp32 -> bf16 (x, w_qkv, w_dense) ----------------
__global__ void cast_all(const float* __restrict__ x, const float* __restrict__ wq,
                         const float* __restrict__ wd, unsigned short* __restrict__ dst) {
  int i = blockIdx.x * blockDim.x + threadIdx.x;  // float4 units
  float4 v;
  if (i < 1048576) v = ((const float4*)x)[i];
  else if (i < 1835008) v = ((const float4*)wq)[i - 1048576];
  else v = ((const float4*)wd)[i - 1835008];
  ushort4 o;
  o.x = f2bf(v.x); o.y = f2bf(v.y); o.z = f2bf(v.z); o.w = f2bf(v.w);
  ((ushort4*)dst)[i] = o;
}

// ---------------- GEMM1 fused: 128x192 tile, BK=64, 512 thr = 8 waves -------
// 512 blocks x 80KB LDS = 2 blocks/CU (4 waves/SIMD): cross-block TLP hides
// load latency. One barrier per K-tile. Swizzled LDS (0 conflicts).
// Fused epilogue: rope(q,k) -> qkv bf16; v -> vt[b,h,d,s] (transpose).
__global__ __launch_bounds__(512, 2) void gemm_qkv(
    const unsigned short* __restrict__ A, const unsigned short* __restrict__ Bw,
    const float* __restrict__ bias, unsigned short* __restrict__ qkvout,
    unsigned short* __restrict__ vtout,
    const float* __restrict__ fc, const float* __restrict__ fs) {
  const int K = 1024, NT = 16;
  __shared__ __align__(16) unsigned short Ah[2][2][128 * 32];  // 32 KB
  __shared__ __align__(16) unsigned short Bh[2][2][192 * 32];  // 48 KB
  const int tid = threadIdx.x;
  const int w = tid >> 6, l = tid & 63;
  const int lg = l >> 4, lr = l & 15;
  const int wm = w >> 2, wn = w & 3;          // 2m x 4n wave grid
  // XCD-bijective swizzle (nwg = 512, % 8 == 0)
  int id = blockIdx.y * gridDim.x + blockIdx.x;
  const int nwg = gridDim.x * gridDim.y;
  id = (id & 7) * (nwg >> 3) + (id >> 3);
  const int bx = id % gridDim.x, by = id / gridDim.x;
  const int mbase = by * 128, nbase = bx * 192;

  const unsigned short *as0, *bs0, *bs1, *bs2;
  {
    int r_ = tid >> 2, s_ = (tid & 3) ^ ((r_ >> 1) & 3);
    as0 = A + (size_t)(mbase + r_) * K + s_ * 8;
    bs0 = Bw + (size_t)(nbase + r_) * K + s_ * 8;
    int cb2 = 512 + tid;
    int h2 = cb2 >= 768;
    int cw2 = cb2 - h2 * 768;
    int r2 = cw2 >> 2, s2 = (cw2 & 3) ^ ((r2 >> 1) & 3);
    bs1 = Bw + (size_t)(nbase + r2) * K + h2 * 32 + s2 * 8;
    int cw3 = 256 + tid;
    int r3 = cw3 >> 2, s3 = (cw3 & 3) ^ ((r3 >> 1) & 3);
    bs2 = Bw + (size_t)(nbase + r3) * K + 32 + s3 * 8;
  }
#define STAGE(buf, k0)                                                        \
  GLDS(&Ah[buf][0][0] + tid * 8, as0 + (k0));                                 \
  GLDS(&Ah[buf][0][0] + 4096 + tid * 8, as0 + 32 + (k0));                     \
  GLDS(&Bh[buf][0][0] + tid * 8, bs0 + (k0));                                 \
  GLDS(&Bh[buf][0][0] + (512 + tid) * 8, bs1 + (k0));                         \
  GLDS(&Bh[buf][0][0] + (1024 + tid) * 8, bs2 + (k0));

  STAGE(0, 0);
  __syncthreads();

  f32x4 acc[4][3] = {};
  for (int t = 0; t < NT; ++t) {
    const int cur = t & 1;
    if (t + 1 < NT) { STAGE(cur ^ 1, (t + 1) * 64); }
#pragma unroll
    for (int h = 0; h < 2; ++h) {
      bf16x8 bfr[3], af[4];
#pragma unroll
      for (int ni = 0; ni < 3; ++ni) {
        int row = wn * 48 + ni * 16 + lr;
        bfr[ni] = *(const bf16x8*)(&Bh[cur][h][row * 32 + ((lg ^ ((row >> 1) & 3)) << 3)]);
      }
#pragma unroll
      for (int j = 0; j < 4; ++j) {
        int row = wm * 64 + j * 16 + lr;
        af[j] = *(const bf16x8*)(&Ah[cur][h][row * 32 + ((lg ^ ((row >> 1) & 3)) << 3)]);
      }
      __builtin_amdgcn_s_setprio(1);
#pragma unroll
      for (int j = 0; j < 4; ++j)
#pragma unroll
        for (int ni = 0; ni < 3; ++ni)
          acc[j][ni] = __builtin_amdgcn_mfma_f32_16x16x32_bf16(
              af[j], bfr[ni], acc[j][ni], 0, 0, 0);
      __builtin_amdgcn_s_setprio(0);
    }
    __syncthreads();
  }
#undef STAGE

  // ---------------- fused epilogue ----------------
#pragma unroll
  for (int mi = 0; mi < 4; ++mi)
#pragma unroll
    for (int ni = 0; ni < 3; ++ni) {
      int col = nbase + wn * 48 + ni * 16 + lr;
      float bi = bias[col];
      int row0 = mbase + wm * 64 + mi * 16 + lg * 4;
      float o4[4];
#pragma unroll
      for (int r = 0; r < 4; ++r) o4[r] = acc[mi][ni][r] + bi;
      int sect = col >> 10;
      int d = col & 63;
      int srow0 = row0 & 2047;
      if (sect < 2) {
        int p = d >> 1;
#pragma unroll
        for (int r = 0; r < 4; ++r) {
          float vp = __shfl_xor(o4[r], 1);
          float c = fc[(srow0 + r) * 32 + p];
          float s = fs[(srow0 + r) * 32 + p];
          float o = (d & 1) ? (vp * s + o4[r] * c) : (o4[r] * c - vp * s);
          qkvout[(size_t)(row0 + r) * 3072 + col] = f2bf(o);
        }
      } else {
        int bh = (row0 >> 11) * 16 + ((col >> 6) & 15);
        uint2 o;
        o.x = pkcvt(o4[0], o4[1]);
        o.y = pkcvt(o4[2], o4[3]);
        *(uint2*)&vtout[((size_t)(bh * 64 + d)) * 2048 + srow0] = o;
      }
    }
}

// ---------------- GEMM: 128x128 m97 structure (GEMM2, fp32 out) ------
__global__ __launch_bounds__(256) void gemm_bt(
    const unsigned short* __restrict__ A, const unsigned short* __restrict__ Bw,
    const float* __restrict__ bias, float* __restrict__ Cout,
    int M, int N, int K) {
  __shared__ __align__(16) unsigned short As[128 * 32];
  __shared__ __align__(16) unsigned short Bs[128 * 32];
  const int tid = threadIdx.x;
  const int w = tid >> 6, l = tid & 63;
  const int lg = l >> 4, lr = l & 15;
  const int mbase = blockIdx.y * 128, nbase = blockIdx.x * 128;
  const int wr = w >> 1, wc = w & 1;
  f32x4 acc[4][4] = {};

  for (int k0 = 0; k0 < K; k0 += 32) {
#pragma unroll
    for (int r = 0; r < 2; ++r) {
      int c = r * 256 + w * 64 + l;
      int row = c >> 2, c8 = c & 3;
      GLDS(As + c * 8, A + (size_t)(mbase + row) * K + k0 + c8 * 8);
      GLDS(Bs + c * 8, Bw + (size_t)(nbase + row) * K + k0 + c8 * 8);
    }
    __syncthreads();
    bf16x8 af[4], bfr[4];
#pragma unroll
    for (int mi = 0; mi < 4; ++mi)
      af[mi] = *(const bf16x8*)(As + (wr * 64 + mi * 16 + lr) * 32 + lg * 8);
#pragma unroll
    for (int ni = 0; ni < 4; ++ni)
      bfr[ni] = *(const bf16x8*)(Bs + (wc * 64 + ni * 16 + lr) * 32 + lg * 8);
#pragma unroll
    for (int mi = 0; mi < 4; ++mi)
#pragma unroll
      for (int ni = 0; ni < 4; ++ni)
        acc[mi][ni] = __builtin_amdgcn_mfma_f32_16x16x32_bf16(
            af[mi], bfr[ni], acc[mi][ni], 0, 0, 0);
    __syncthreads();
  }

#pragma unroll
  for (int mi = 0; mi < 4; ++mi) {
#pragma unroll
    for (int ni = 0; ni < 4; ++ni) {
      int col = nbase + wc * 64 + ni * 16 + lr;
      float bi = bias[col];
#pragma unroll
      for (int r = 0; r < 4; ++r) {
        int row = mbase + wr * 64 + mi * 16 + lg * 4 + r;
        Cout[(size_t)row * N + col] = acc[mi][ni][r] + bi;
      }
    }
  }
}

// ---------------- Flash attention (causal), split-K swapped form ----------------
// Block = (bh, 64 q-rows), 4 waves (256 thr) = 2 q-groups (wq, 32 rows each)
// x 2 k-slices (wk). ka/va LDS reads SHARED across the wave's 2 q-subtiles
// (mi) -> LDS traffic/tile ~0.67x of the 8-wave form, MFMA density 2x.
// K/V staged via global_load_lds with PRE-SWIZZLED global source + linear LDS
// dst (rule-21 involution); 48KB LDS -> 3 blocks/CU; TLP hides stage drain.
__global__ __launch_bounds__(256, 3) void attn(
    const unsigned short* __restrict__ qkv, const unsigned short* __restrict__ vt,
    unsigned short* __restrict__ ctx) {
  __shared__ __align__(16) unsigned short Ks[2][64 * 64];
  __shared__ __align__(16) unsigned short Vs[2][64 * 64];
  __shared__ __align__(16) unsigned short Ps[4][32 * 64];
  int did = blockIdx.x;                  // 1024 blocks
  int x = did & 7, rest = did >> 3;      // XCD x owns bh 4x..4x+3
  int bh = x * 4 + (rest & 3);
  int qi = 31 - (rest >> 2);             // LPT: heavy q-tiles first
  int b = bh >> 4, h = bh & 15;
  int qbase = qi * 64;
  int tid = threadIdx.x;
  int w = tid >> 6, l = tid & 63;
  int lg = l >> 4, lr = l & 15;
  int wq = w & 1, wk = w >> 1;
  int qw = wq * 32;                      // wave's local q base

  // Q fragments for q-rows qbase + qw + mi*16 + lr, log2-domain pre-scale
  bf16x8 qb[2][2];
#pragma unroll
  for (int mi = 0; mi < 2; ++mi)
#pragma unroll
    for (int kc = 0; kc < 2; ++kc) {
      s16x8 qr = *(const s16x8*)(qkv +
          (size_t)(b * Ss + qbase + qw + mi * 16 + lr) * 3072 + h * 64 + kc * 32 + lg * 8);
      bf16x8 qs;
#pragma unroll
      for (int e = 0; e < 8; ++e)
        qs[e] = (__bf16)(bf2f((unsigned short)qr[e]) * 0.18033688f);
      qb[mi][kc] = qs;
    }

  // GLDS staging: thread covers chunks c1=tid, c2=256+tid of each 512-chunk
  // tile; global source pre-swizzled (col = (slot^(row&7))*8), LDS dst linear.
  int c1 = tid, c2 = 256 + tid;
  int r1 = c1 >> 3, s1 = ((c1 & 7) ^ (r1 & 7)) * 8;
  int r2 = c2 >> 3, s2 = ((c2 & 7) ^ (r2 & 7)) * 8;
  const unsigned short* kg1 = qkv + ((size_t)(b * Ss) + r1) * 3072 + 1024 + h * 64 + s1;
  const unsigned short* kg2 = qkv + ((size_t)(b * Ss) + r2) * 3072 + 1024 + h * 64 + s2;
  const unsigned short* vg1 = vt + ((size_t)bh * 64 + r1) * 2048 + s1;
  const unsigned short* vg2 = vt + ((size_t)bh * 64 + r2) * 2048 + s2;
#define STAGEKV(kt)                                                           \
  {                                                                           \
    int tt_ = (kt) & 1;                                                       \
    GLDS(&Ks[tt_][0] + c1 * 8, kg1 + (size_t)(kt) * 64 * 3072);               \
    GLDS(&Ks[tt_][0] + c2 * 8, kg2 + (size_t)(kt) * 64 * 3072);               \
    GLDS(&Vs[tt_][0] + c1 * 8, vg1 + (kt) * 64);                              \
    GLDS(&Vs[tt_][0] + c2 * 8, vg2 + (kt) * 64);                              \
  }

  int nkt = qi + 1;
  int nsup = (nkt + 1) >> 1;

  STAGEKV(0);
  if (1 < nkt) STAGEKV(1);
  __syncthreads();

  f32x4 acc[4][2] = {};       // ctx^T partial: acc[nd][mi], rows d, cols q(=lr)
  float mrow[2] = {-1e30f, -1e30f}, lsum[2] = {0.f, 0.f};

  for (int j = 0; j < nsup; ++j) {
    int kt = 2 * j + wk;
    if (kt < nkt) {
      // S^T = K Q^T (log2-scaled); ka shared across mi
      f32x4 st[4][2] = {};
      __builtin_amdgcn_s_setprio(1);
#pragma unroll
      for (int kc = 0; kc < 2; ++kc) {
#pragma unroll
        for (int ni = 0; ni < 4; ++ni) {
          bf16x8 ka = *(const bf16x8*)&Ks[wk][swz(ni * 16 + lr, kc * 32 + lg * 8)];
#pragma unroll
          for (int mi = 0; mi < 2; ++mi)
            st[ni][mi] = __builtin_amdgcn_mfma_f32_16x16x32_bf16(
                ka, qb[mi][kc], st[ni][mi], 0, 0, 0);
        }
      }
      __builtin_amdgcn_s_setprio(0);

      float tm[2] = {-1e30f, -1e30f};
      if (kt == qi) {               // diagonal tile: causal mask
#pragma unroll
        for (int mi = 0; mi < 2; ++mi) {
          int rq = qw + mi * 16 + lr;
#pragma unroll
          for (int ni = 0; ni < 4; ++ni)
#pragma unroll
            for (int r4 = 0; r4 < 4; ++r4) {
              float s = st[ni][mi][r4];
              if (ni * 16 + lg * 4 + r4 > rq) s = -1e30f;
              st[ni][mi][r4] = s;
              tm[mi] = fmaxf(tm[mi], s);
            }
        }
      } else {
#pragma unroll
        for (int mi = 0; mi < 2; ++mi)
#pragma unroll
          for (int ni = 0; ni < 4; ++ni)
#pragma unroll
            for (int r4 = 0; r4 < 4; ++r4) tm[mi] = fmaxf(tm[mi], st[ni][mi][r4]);
      }
      // defer-max: cross-lane reduce + rescale only when bound trips
      bool ok = (tm[0] <= mrow[0] + 8.0f) && (tm[1] <= mrow[1] + 8.0f);
      if (!__all(ok)) {
#pragma unroll
        for (int mi = 0; mi < 2; ++mi) {
          float t = fmaxf(tm[mi], __shfl_xor(tm[mi], 16));
          t = fmaxf(t, __shfl_xor(t, 32));
          float mnew = fmaxf(mrow[mi], t);
          float alpha = ex2(mrow[mi] - mnew);
          lsum[mi] *= alpha;
#pragma unroll
          for (int nd = 0; nd < 4; ++nd)
#pragma unroll
            for (int r4 = 0; r4 < 4; ++r4) acc[nd][mi][r4] *= alpha;
          mrow[mi] = mnew;
        }
      }
#pragma unroll
      for (int mi = 0; mi < 2; ++mi) {
        float sum = 0.f;
#pragma unroll
        for (int ni = 0; ni < 4; ++ni)
#pragma unroll
          for (int r4 = 0; r4 < 4; ++r4) {
            float pe = ex2(st[ni][mi][r4] - mrow[mi]);
            st[ni][mi][r4] = pe;
            sum += pe;
          }
        lsum[mi] += sum;
        // P[q][k] -> per-wave LDS (swizzled)
#pragma unroll
        for (int ni = 0; ni < 4; ++ni) {
          uint2 wv;
          wv.x = pkcvt(st[ni][mi][0], st[ni][mi][1]);
          wv.y = pkcvt(st[ni][mi][2], st[ni][mi][3]);
          *(uint2*)&Ps[w][swz(mi * 16 + lr, ni * 16 + lg * 4)] = wv;
        }
      }
      // ctx^T += V^T P^T ; va shared across mi
      __builtin_amdgcn_s_setprio(1);
#pragma unroll
      for (int kc = 0; kc < 2; ++kc) {
        bf16x8 pbf[2];
#pragma unroll
        for (int mi = 0; mi < 2; ++mi)
          pbf[mi] = *(const bf16x8*)&Ps[w][swz(mi * 16 + lr, kc * 32 + lg * 8)];
#pragma unroll
        for (int nd = 0; nd < 4; ++nd) {
          bf16x8 va = *(const bf16x8*)&Vs[wk][swz(nd * 16 + lr, kc * 32 + lg * 8)];
#pragma unroll
          for (int mi = 0; mi < 2; ++mi)
            acc[nd][mi] = __builtin_amdgcn_mfma_f32_16x16x32_bf16(
                va, pbf[mi], acc[nd][mi], 0, 0, 0);
        }
      }
      __builtin_amdgcn_s_setprio(0);
    }

    if (j + 1 < nsup) {
      __syncthreads();              // all waves done reading pair j
      int t0 = 2 * (j + 1), t1 = t0 + 1;
      STAGEKV(t0);
      if (t1 < nkt) STAGEKV(t1);
      __syncthreads();              // GLDS drained (compiler vmcnt0 at barrier)
    }
  }
#undef STAGEKV

  // ---- combine the two k-slices of each q-group ----
#pragma unroll
  for (int mi = 0; mi < 2; ++mi) {
    lsum[mi] += __shfl_xor(lsum[mi], 16);
    lsum[mi] += __shfl_xor(lsum[mi], 32);
  }
  __syncthreads();                  // done with K/V; reuse as scratch
  float* aS0 = (float*)Ks;          // [2 wq][64 l][16] = 8KB (mi=0)
  float* aS1 = (float*)Vs;          // mi=1
  float* mlS = (float*)Ps;          // [2 wq][64 l][4]
  if (wk == 1) {
    int base = (wq * 64 + l) * 16;
#pragma unroll
    for (int nd = 0; nd < 4; ++nd) {
      *(f32x4*)(aS0 + base + nd * 4) = acc[nd][0];
      *(f32x4*)(aS1 + base + nd * 4) = acc[nd][1];
    }
    int mb = (wq * 64 + l) * 4;
    mlS[mb] = mrow[0]; mlS[mb + 1] = lsum[0];
    mlS[mb + 2] = mrow[1]; mlS[mb + 3] = lsum[1];
  }
  __syncthreads();
  if (wk == 0) {
    int base = (wq * 64 + l) * 16;
    int mb = (wq * 64 + l) * 4;
#pragma unroll
    for (int mi = 0; mi < 2; ++mi) {
      const float* as = (mi ? aS1 : aS0) + base;
      float m1 = mlS[mb + mi * 2], l1 = mlS[mb + mi * 2 + 1];
      float M = fmaxf(mrow[mi], m1);
      float s0 = ex2(mrow[mi] - M), s1 = ex2(m1 - M);
      float inv = 1.0f / (lsum[mi] * s0 + l1 * s1);
      float f0 = s0 * inv, f1 = s1 * inv;
      int qg = qbase + qw + mi * 16 + lr;
#pragma unroll
      for (int nd = 0; nd < 4; ++nd) {
        f32x4 a1 = *(const f32x4*)(as + nd * 4);
        uint2 o;
        o.x = pkcvt(acc[nd][mi][0] * f0 + a1[0] * f1,
                    acc[nd][mi][1] * f0 + a1[1] * f1);
        o.y = pkcvt(acc[nd][mi][2] * f0 + a1[2] * f1,
                    acc[nd][mi][3] * f0 + a1[3] * f1);
        *(uint2*)&ctx[((size_t)(b * Ss) + qg) * 1024 + h * 64 + nd * 16 + lg * 4] = o;
      }
    }
  }
}

extern "C" void kernel_launch(void* const* d_in, const int* in_sizes, int n_in,
                              void* d_out, int out_size, void* d_ws, size_t ws_size,
                              hipStream_t stream) {
  const float* x       = (const float*)d_in[0];
  const float* w_qkv   = (const float*)d_in[1];
  const float* b_qkv   = (const float*)d_in[2];
  const float* w_dense = (const float*)d_in[3];
  const float* b_dense = (const float*)d_in[4];
  const float* fc      = (const float*)d_in[5];
  const float* fs      = (const float*)d_in[6];
  float* out = (float*)d_out;

  char* ws = (char*)d_ws;
  unsigned short* xb    = (unsigned short*)(ws);                        // 8 MB
  unsigned short* wqkvb = (unsigned short*)(ws + (8ull  << 20));        // 6 MB
  unsigned short* wdb   = (unsigned short*)(ws + (14ull << 20));        // 2 MB
  unsigned short* qkvb  = (unsigned short*)(ws + (16ull << 20));        // 24 MB
  unsigned short* vt    = (unsigned short*)(ws + (40ull << 20));        // 8 MB

  cast_all<<<8192, 256, 0, stream>>>(x, w_qkv, w_dense, xb);

  // GEMM1 fused (128x192 tiles -> 512 blocks = 2/CU):
  // rope(q,k) -> qkvb ; v -> vt (transposed)
  gemm_qkv<<<dim3(16, 32), 512, 0, stream>>>(xb, wqkvb, b_qkv, qkvb, vt, fc, fs);
  attn<<<1024, 256, 0, stream>>>(qkvb, vt, xb /* ctx reuse */);
  gemm_bt<<<dim3(8, 32), 256, 0, stream>>>(xb, wdb, b_dense, out,
                                           4096, 1024, 1024);
}

// Round 17
// 96.615 us; speedup vs baseline: 1.1665x; 1.0820x over previous
//
#include <hip/hip_runtime.h>
#include <stdint.h>

#define Bb 2
#define Ss 2048
#define Dd 1024
#define Hh 16
#define HDd 64
// M = B*S = 4096

typedef float f32x4 __attribute__((ext_vector_type(4)));
typedef __bf16 bf16x8 __attribute__((ext_vector_type(8)));
typedef __bf16 bf16x2 __attribute__((ext_vector_type(2)));
typedef short s16x8 __attribute__((ext_vector_type(8)));

__device__ inline unsigned short f2bf(float f) {
  unsigned u = __builtin_bit_cast(unsigned, f);
  u += 0x7fffu + ((u >> 16) & 1u);
  return (unsigned short)(u >> 16);
}
__device__ inline float bf2f(unsigned short h) {
  unsigned u = ((unsigned)h) << 16;
  return __builtin_bit_cast(float, u);
}
// native-cast pair pack: compiler fuses to v_cvt_pk_bf16_f32 (RNE)
__device__ inline unsigned pkcvt(float a, float b) {
  bf16x2 v;
  v[0] = (__bf16)a;
  v[1] = (__bf16)b;
  return __builtin_bit_cast(unsigned, v);
}
// native v_exp_f32 (2^x); avoid OCML precise exp2 path
__device__ inline float ex2(float x) {
#if __has_builtin(__builtin_amdgcn_exp2f)
  return __builtin_amdgcn_exp2f(x);
#else
  float r;
  asm("v_exp_f32 %0, %1\n\ts_nop 1" : "=v"(r) : "v"(x));
  return r;
#endif
}
// XOR-swizzled short-index into a [rows][64-short] LDS tile (attn).
__device__ inline int swz(int row, int soff) {
  return (row << 6) + ((((soff >> 3) ^ (row & 7)) << 3) | (soff & 7));
}

#define GLDS(dst, src)                                                        \
  __builtin_amdgcn_global_load_lds(                                           \
      (const __attribute__((address_space(1))) void*)(src),                   \
      (__attribute__((address_space(3))) void*)(dst), 16, 0, 0)

// ---------------- fused cast fp32 -> bf16 (x, w_qkv, w_dense) ----------------
__global__ void cast_all(const float* __restrict__ x, const float* __restrict__ wq,
                         const float* __restrict__ wd, unsigned short* __restrict__ dst) {
  int i = blockIdx.x * blockDim.x + threadIdx.x;  // float4 units
  float4 v;
  if (i < 1048576) v = ((const float4*)x)[i];
  else if (i < 1835008) v = ((const float4*)wq)[i - 1048576];
  else v = ((const float4*)wd)[i - 1835008];
  ushort4 o;
  o.x = f2bf(v.x); o.y = f2bf(v.y); o.z = f2bf(v.z); o.w = f2bf(v.w);
  ((ushort4*)dst)[i] = o;
}

// ---------------- GEMM1 fused: 128x192 tile, BK=64, 512 thr = 8 waves -------
// 512 blocks x 80KB LDS = 2 blocks/CU (4 waves/SIMD): cross-block TLP hides
// load latency. One barrier per K-tile. Swizzled LDS (0 conflicts).
// Fused epilogue: rope(q,k) -> qkv bf16; v -> vt[b,h,d,s] (transpose).
__global__ __launch_bounds__(512, 2) void gemm_qkv(
    const unsigned short* __restrict__ A, const unsigned short* __restrict__ Bw,
    const float* __restrict__ bias, unsigned short* __restrict__ qkvout,
    unsigned short* __restrict__ vtout,
    const float* __restrict__ fc, const float* __restrict__ fs) {
  const int K = 1024, NT = 16;
  __shared__ __align__(16) unsigned short Ah[2][2][128 * 32];  // 32 KB
  __shared__ __align__(16) unsigned short Bh[2][2][192 * 32];  // 48 KB
  const int tid = threadIdx.x;
  const int w = tid >> 6, l = tid & 63;
  const int lg = l >> 4, lr = l & 15;
  const int wm = w >> 2, wn = w & 3;          // 2m x 4n wave grid
  // XCD-bijective swizzle (nwg = 512, % 8 == 0)
  int id = blockIdx.y * gridDim.x + blockIdx.x;
  const int nwg = gridDim.x * gridDim.y;
  id = (id & 7) * (nwg >> 3) + (id >> 3);
  const int bx = id % gridDim.x, by = id / gridDim.x;
  const int mbase = by * 128, nbase = bx * 192;

  const unsigned short *as0, *bs0, *bs1, *bs2;
  {
    int r_ = tid >> 2, s_ = (tid & 3) ^ ((r_ >> 1) & 3);
    as0 = A + (size_t)(mbase + r_) * K + s_ * 8;
    bs0 = Bw + (size_t)(nbase + r_) * K + s_ * 8;
    int cb2 = 512 + tid;
    int h2 = cb2 >= 768;
    int cw2 = cb2 - h2 * 768;
    int r2 = cw2 >> 2, s2 = (cw2 & 3) ^ ((r2 >> 1) & 3);
    bs1 = Bw + (size_t)(nbase + r2) * K + h2 * 32 + s2 * 8;
    int cw3 = 256 + tid;
    int r3 = cw3 >> 2, s3 = (cw3 & 3) ^ ((r3 >> 1) & 3);
    bs2 = Bw + (size_t)(nbase + r3) * K + 32 + s3 * 8;
  }
#define STAGE(buf, k0)                                                        \
  GLDS(&Ah[buf][0][0] + tid * 8, as0 + (k0));                                 \
  GLDS(&Ah[buf][0][0] + 4096 + tid * 8, as0 + 32 + (k0));                     \
  GLDS(&Bh[buf][0][0] + tid * 8, bs0 + (k0));                                 \
  GLDS(&Bh[buf][0][0] + (512 + tid) * 8, bs1 + (k0));                         \
  GLDS(&Bh[buf][0][0] + (1024 + tid) * 8, bs2 + (k0));

  STAGE(0, 0);
  __syncthreads();

  f32x4 acc[4][3] = {};
  for (int t = 0; t < NT; ++t) {
    const int cur = t & 1;
    if (t + 1 < NT) { STAGE(cur ^ 1, (t + 1) * 64); }
#pragma unroll
    for (int h = 0; h < 2; ++h) {
      bf16x8 bfr[3], af[4];
#pragma unroll
      for (int ni = 0; ni < 3; ++ni) {
        int row = wn * 48 + ni * 16 + lr;
        bfr[ni] = *(const bf16x8*)(&Bh[cur][h][row * 32 + ((lg ^ ((row >> 1) & 3)) << 3)]);
      }
#pragma unroll
      for (int j = 0; j < 4; ++j) {
        int row = wm * 64 + j * 16 + lr;
        af[j] = *(const bf16x8*)(&Ah[cur][h][row * 32 + ((lg ^ ((row >> 1) & 3)) << 3)]);
      }
      __builtin_amdgcn_s_setprio(1);
#pragma unroll
      for (int j = 0; j < 4; ++j)
#pragma unroll
        for (int ni = 0; ni < 3; ++ni)
          acc[j][ni] = __builtin_amdgcn_mfma_f32_16x16x32_bf16(
              af[j], bfr[ni], acc[j][ni], 0, 0, 0);
      __builtin_amdgcn_s_setprio(0);
    }
    __syncthreads();
  }
#undef STAGE

  // ---------------- fused epilogue ----------------
#pragma unroll
  for (int mi = 0; mi < 4; ++mi)
#pragma unroll
    for (int ni = 0; ni < 3; ++ni) {
      int col = nbase + wn * 48 + ni * 16 + lr;
      float bi = bias[col];
      int row0 = mbase + wm * 64 + mi * 16 + lg * 4;
      float o4[4];
#pragma unroll
      for (int r = 0; r < 4; ++r) o4[r] = acc[mi][ni][r] + bi;
      int sect = col >> 10;
      int d = col & 63;
      int srow0 = row0 & 2047;
      if (sect < 2) {
        int p = d >> 1;
#pragma unroll
        for (int r = 0; r < 4; ++r) {
          float vp = __shfl_xor(o4[r], 1);
          float c = fc[(srow0 + r) * 32 + p];
          float s = fs[(srow0 + r) * 32 + p];
          float o = (d & 1) ? (vp * s + o4[r] * c) : (o4[r] * c - vp * s);
          qkvout[(size_t)(row0 + r) * 3072 + col] = f2bf(o);
        }
      } else {
        int bh = (row0 >> 11) * 16 + ((col >> 6) & 15);
        uint2 o;
        o.x = pkcvt(o4[0], o4[1]);
        o.y = pkcvt(o4[2], o4[3]);
        *(uint2*)&vtout[((size_t)(bh * 64 + d)) * 2048 + srow0] = o;
      }
    }
}

// ---------------- GEMM2: 64x128 tile, BK=32, 256 thr = 4 waves (2m x 2n) ----
// 512 blocks (grid 8x64) = 2 blocks/CU: TLP hides the stage drain. Swizzled
// LDS (pre-swizzled global src + linear GLDS dst + swizzled reads) kills the
// 3.1M bank conflicts measured on the old unswizzled m97 layout (r12 PMC).
__global__ __launch_bounds__(256, 2) void gemm_out(
    const unsigned short* __restrict__ A, const unsigned short* __restrict__ Bw,
    const float* __restrict__ bias, float* __restrict__ Cout) {
  const int M = 4096, N = 1024, K = 1024;
  __shared__ __align__(16) unsigned short As[64 * 32];    // 4 KB
  __shared__ __align__(16) unsigned short Bs[128 * 32];   // 8 KB
  const int tid = threadIdx.x;
  const int w = tid >> 6, l = tid & 63;
  const int lg = l >> 4, lr = l & 15;
  const int wm = w >> 1, wn = w & 1;
  // XCD-bijective swizzle (512 blocks, % 8 == 0)
  int id = blockIdx.y * gridDim.x + blockIdx.x;
  const int nwg = gridDim.x * gridDim.y;
  id = (id & 7) * (nwg >> 3) + (id >> 3);
  const int bx = id % gridDim.x, by = id / gridDim.x;
  const int mbase = by * 64, nbase = bx * 128;

  // staging sources, pre-swizzled: chunk c -> row c>>2, slot (c&3)^((row>>1)&3)
  const unsigned short *as0, *bs0, *bs1;
  {
    int r_ = tid >> 2, s_ = (tid & 3) ^ ((r_ >> 1) & 3);
    as0 = A + (size_t)(mbase + r_) * K + s_ * 8;
    bs0 = Bw + (size_t)(nbase + r_) * K + s_ * 8;
    int r2 = 64 + r_, s2 = (tid & 3) ^ ((r2 >> 1) & 3);
    bs1 = Bw + (size_t)(nbase + r2) * K + s2 * 8;
  }

  f32x4 acc[2][4] = {};
  for (int k0 = 0; k0 < K; k0 += 32) {
    GLDS(As + tid * 8, as0 + k0);
    GLDS(Bs + tid * 8, bs0 + k0);
    GLDS(Bs + (256 + tid) * 8, bs1 + k0);
    __syncthreads();
    bf16x8 af[2], bfr[4];
#pragma unroll
    for (int mi = 0; mi < 2; ++mi) {
      int row = wm * 32 + mi * 16 + lr;
      af[mi] = *(const bf16x8*)(As + row * 32 + ((lg ^ ((row >> 1) & 3)) << 3));
    }
#pragma unroll
    for (int ni = 0; ni < 4; ++ni) {
      int row = wn * 64 + ni * 16 + lr;
      bfr[ni] = *(const bf16x8*)(Bs + row * 32 + ((lg ^ ((row >> 1) & 3)) << 3));
    }
    __builtin_amdgcn_s_setprio(1);
#pragma unroll
    for (int mi = 0; mi < 2; ++mi)
#pragma unroll
      for (int ni = 0; ni < 4; ++ni)
        acc[mi][ni] = __builtin_amdgcn_mfma_f32_16x16x32_bf16(
            af[mi], bfr[ni], acc[mi][ni], 0, 0, 0);
    __builtin_amdgcn_s_setprio(0);
    __syncthreads();
  }

#pragma unroll
  for (int mi = 0; mi < 2; ++mi) {
#pragma unroll
    for (int ni = 0; ni < 4; ++ni) {
      int col = nbase + wn * 64 + ni * 16 + lr;
      float bi = bias[col];
#pragma unroll
      for (int r = 0; r < 4; ++r) {
        int row = mbase + wm * 32 + mi * 16 + lg * 4 + r;
        Cout[(size_t)row * N + col] = acc[mi][ni][r] + bi;
      }
    }
  }
}

// ---------------- Flash attention (causal), split-K swapped form ----------------
// Block = (bh, 64 q-rows), 4 waves (256 thr) = 2 q-groups (wq, 32 rows each)
// x 2 k-slices (wk). ka/va LDS reads SHARED across the wave's 2 q-subtiles
// (mi) -> LDS traffic/tile ~0.67x of the 8-wave form, MFMA density 2x.
// K/V staged via global_load_lds with PRE-SWIZZLED global source + linear LDS
// dst (rule-21 involution); 48KB LDS -> 3 blocks/CU; TLP hides stage drain.
__global__ __launch_bounds__(256, 3) void attn(
    const unsigned short* __restrict__ qkv, const unsigned short* __restrict__ vt,
    unsigned short* __restrict__ ctx) {
  __shared__ __align__(16) unsigned short Ks[2][64 * 64];
  __shared__ __align__(16) unsigned short Vs[2][64 * 64];
  __shared__ __align__(16) unsigned short Ps[4][32 * 64];
  int did = blockIdx.x;                  // 1024 blocks
  int x = did & 7, rest = did >> 3;      // XCD x owns bh 4x..4x+3
  int bh = x * 4 + (rest & 3);
  int qi = 31 - (rest >> 2);             // LPT: heavy q-tiles first
  int b = bh >> 4, h = bh & 15;
  int qbase = qi * 64;
  int tid = threadIdx.x;
  int w = tid >> 6, l = tid & 63;
  int lg = l >> 4, lr = l & 15;
  int wq = w & 1, wk = w >> 1;
  int qw = wq * 32;                      // wave's local q base

  // Q fragments for q-rows qbase + qw + mi*16 + lr, log2-domain pre-scale
  bf16x8 qb[2][2];
#pragma unroll
  for (int mi = 0; mi < 2; ++mi)
#pragma unroll
    for (int kc = 0; kc < 2; ++kc) {
      s16x8 qr = *(const s16x8*)(qkv +
          (size_t)(b * Ss + qbase + qw + mi * 16 + lr) * 3072 + h * 64 + kc * 32 + lg * 8);
      bf16x8 qs;
#pragma unroll
      for (int e = 0; e < 8; ++e)
        qs[e] = (__bf16)(bf2f((unsigned short)qr[e]) * 0.18033688f);
      qb[mi][kc] = qs;
    }

  // GLDS staging: thread covers chunks c1=tid, c2=256+tid of each 512-chunk
  // tile; global source pre-swizzled (col = (slot^(row&7))*8), LDS dst linear.
  int c1 = tid, c2 = 256 + tid;
  int r1 = c1 >> 3, s1 = ((c1 & 7) ^ (r1 & 7)) * 8;
  int r2 = c2 >> 3, s2 = ((c2 & 7) ^ (r2 & 7)) * 8;
  const unsigned short* kg1 = qkv + ((size_t)(b * Ss) + r1) * 3072 + 1024 + h * 64 + s1;
  const unsigned short* kg2 = qkv + ((size_t)(b * Ss) + r2) * 3072 + 1024 + h * 64 + s2;
  const unsigned short* vg1 = vt + ((size_t)bh * 64 + r1) * 2048 + s1;
  const unsigned short* vg2 = vt + ((size_t)bh * 64 + r2) * 2048 + s2;
#define STAGEKV(kt)                                                           \
  {                                                                           \
    int tt_ = (kt) & 1;                                                       \
    GLDS(&Ks[tt_][0] + c1 * 8, kg1 + (size_t)(kt) * 64 * 3072);               \
    GLDS(&Ks[tt_][0] + c2 * 8, kg2 + (size_t)(kt) * 64 * 3072);               \
    GLDS(&Vs[tt_][0] + c1 * 8, vg1 + (kt) * 64);                              \
    GLDS(&Vs[tt_][0] + c2 * 8, vg2 + (kt) * 64);                              \
  }

  int nkt = qi + 1;
  int nsup = (nkt + 1) >> 1;

  STAGEKV(0);
  if (1 < nkt) STAGEKV(1);
  __syncthreads();

  f32x4 acc[4][2] = {};       // ctx^T partial: acc[nd][mi], rows d, cols q(=lr)
  float mrow[2] = {-1e30f, -1e30f}, lsum[2] = {0.f, 0.f};

  for (int j = 0; j < nsup; ++j) {
    int kt = 2 * j + wk;
    if (kt < nkt) {
      // S^T = K Q^T (log2-scaled); ka shared across mi
      f32x4 st[4][2] = {};
      __builtin_amdgcn_s_setprio(1);
#pragma unroll
      for (int kc = 0; kc < 2; ++kc) {
#pragma unroll
        for (int ni = 0; ni < 4; ++ni) {
          bf16x8 ka = *(const bf16x8*)&Ks[wk][swz(ni * 16 + lr, kc * 32 + lg * 8)];
#pragma unroll
          for (int mi = 0; mi < 2; ++mi)
            st[ni][mi] = __builtin_amdgcn_mfma_f32_16x16x32_bf16(
                ka, qb[mi][kc], st[ni][mi], 0, 0, 0);
        }
      }
      __builtin_amdgcn_s_setprio(0);

      float tm[2] = {-1e30f, -1e30f};
      if (kt == qi) {               // diagonal tile: causal mask
#pragma unroll
        for (int mi = 0; mi < 2; ++mi) {
          int rq = qw + mi * 16 + lr;
#pragma unroll
          for (int ni = 0; ni < 4; ++ni)
#pragma unroll
            for (int r4 = 0; r4 < 4; ++r4) {
              float s = st[ni][mi][r4];
              if (ni * 16 + lg * 4 + r4 > rq) s = -1e30f;
              st[ni][mi][r4] = s;
              tm[mi] = fmaxf(tm[mi], s);
            }
        }
      } else {
#pragma unroll
        for (int mi = 0; mi < 2; ++mi)
#pragma unroll
          for (int ni = 0; ni < 4; ++ni)
#pragma unroll
            for (int r4 = 0; r4 < 4; ++r4) tm[mi] = fmaxf(tm[mi], st[ni][mi][r4]);
      }
      // defer-max: cross-lane reduce + rescale only when bound trips
      bool ok = (tm[0] <= mrow[0] + 8.0f) && (tm[1] <= mrow[1] + 8.0f);
      if (!__all(ok)) {
#pragma unroll
        for (int mi = 0; mi < 2; ++mi) {
          float t = fmaxf(tm[mi], __shfl_xor(tm[mi], 16));
          t = fmaxf(t, __shfl_xor(t, 32));
          float mnew = fmaxf(mrow[mi], t);
          float alpha = ex2(mrow[mi] - mnew);
          lsum[mi] *= alpha;
#pragma unroll
          for (int nd = 0; nd < 4; ++nd)
#pragma unroll
            for (int r4 = 0; r4 < 4; ++r4) acc[nd][mi][r4] *= alpha;
          mrow[mi] = mnew;
        }
      }
#pragma unroll
      for (int mi = 0; mi < 2; ++mi) {
        float sum = 0.f;
#pragma unroll
        for (int ni = 0; ni < 4; ++ni)
#pragma unroll
          for (int r4 = 0; r4 < 4; ++r4) {
            float pe = ex2(st[ni][mi][r4] - mrow[mi]);
            st[ni][mi][r4] = pe;
            sum += pe;
          }
        lsum[mi] += sum;
        // P[q][k] -> per-wave LDS (swizzled)
#pragma unroll
        for (int ni = 0; ni < 4; ++ni) {
          uint2 wv;
          wv.x = pkcvt(st[ni][mi][0], st[ni][mi][1]);
          wv.y = pkcvt(st[ni][mi][2], st[ni][mi][3]);
          *(uint2*)&Ps[w][swz(mi * 16 + lr, ni * 16 + lg * 4)] = wv;
        }
      }
      // ctx^T += V^T P^T ; va shared across mi
      __builtin_amdgcn_s_setprio(1);
#pragma unroll
      for (int kc = 0; kc < 2; ++kc) {
        bf16x8 pbf[2];
#pragma unroll
        for (int mi = 0; mi < 2; ++mi)
          pbf[mi] = *(const bf16x8*)&Ps[w][swz(mi * 16 + lr, kc * 32 + lg * 8)];
#pragma unroll
        for (int nd = 0; nd < 4; ++nd) {
          bf16x8 va = *(const bf16x8*)&Vs[wk][swz(nd * 16 + lr, kc * 32 + lg * 8)];
#pragma unroll
          for (int mi = 0; mi < 2; ++mi)
            acc[nd][mi] = __builtin_amdgcn_mfma_f32_16x16x32_bf16(
                va, pbf[mi], acc[nd][mi], 0, 0, 0);
        }
      }
      __builtin_amdgcn_s_setprio(0);
    }

    if (j + 1 < nsup) {
      __syncthreads();              // all waves done reading pair j
      int t0 = 2 * (j + 1), t1 = t0 + 1;
      STAGEKV(t0);
      if (t1 < nkt) STAGEKV(t1);
      __syncthreads();              // GLDS drained (compiler vmcnt0 at barrier)
    }
  }
#undef STAGEKV

  // ---- combine the two k-slices of each q-group ----
#pragma unroll
  for (int mi = 0; mi < 2; ++mi) {
    lsum[mi] += __shfl_xor(lsum[mi], 16);
    lsum[mi] += __shfl_xor(lsum[mi], 32);
  }
  __syncthreads();                  // done with K/V; reuse as scratch
  float* aS0 = (float*)Ks;          // [2 wq][64 l][16] = 8KB (mi=0)
  float* aS1 = (float*)Vs;          // mi=1
  float* mlS = (float*)Ps;          // [2 wq][64 l][4]
  if (wk == 1) {
    int base = (wq * 64 + l) * 16;
#pragma unroll
    for (int nd = 0; nd < 4; ++nd) {
      *(f32x4*)(aS0 + base + nd * 4) = acc[nd][0];
      *(f32x4*)(aS1 + base + nd * 4) = acc[nd][1];
    }
    int mb = (wq * 64 + l) * 4;
    mlS[mb] = mrow[0]; mlS[mb + 1] = lsum[0];
    mlS[mb + 2] = mrow[1]; mlS[mb + 3] = lsum[1];
  }
  __syncthreads();
  if (wk == 0) {
    int base = (wq * 64 + l) * 16;
    int mb = (wq * 64 + l) * 4;
#pragma unroll
    for (int mi = 0; mi < 2; ++mi) {
      const float* as = (mi ? aS1 : aS0) + base;
      float m1 = mlS[mb + mi * 2], l1 = mlS[mb + mi * 2 + 1];
      float M = fmaxf(mrow[mi], m1);
      float s0 = ex2(mrow[mi] - M), s1 = ex2(m1 - M);
      float inv = 1.0f / (lsum[mi] * s0 + l1 * s1);
      float f0 = s0 * inv, f1 = s1 * inv;
      int qg = qbase + qw + mi * 16 + lr;
#pragma unroll
      for (int nd = 0; nd < 4; ++nd) {
        f32x4 a1 = *(const f32x4*)(as + nd * 4);
        uint2 o;
        o.x = pkcvt(acc[nd][mi][0] * f0 + a1[0] * f1,
                    acc[nd][mi][1] * f0 + a1[1] * f1);
        o.y = pkcvt(acc[nd][mi][2] * f0 + a1[2] * f1,
                    acc[nd][mi][3] * f0 + a1[3] * f1);
        *(uint2*)&ctx[((size_t)(b * Ss) + qg) * 1024 + h * 64 + nd * 16 + lg * 4] = o;
      }
    }
  }
}

extern "C" void kernel_launch(void* const* d_in, const int* in_sizes, int n_in,
                              void* d_out, int out_size, void* d_ws, size_t ws_size,
                              hipStream_t stream) {
  const float* x       = (const float*)d_in[0];
  const float* w_qkv   = (const float*)d_in[1];
  const float* b_qkv   = (const float*)d_in[2];
  const float* w_dense = (const float*)d_in[3];
  const float* b_dense = (const float*)d_in[4];
  const float* fc      = (const float*)d_in[5];
  const float* fs      = (const float*)d_in[6];
  float* out = (float*)d_out;

  char* ws = (char*)d_ws;
  unsigned short* xb    = (unsigned short*)(ws);                        // 8 MB
  unsigned short* wqkvb = (unsigned short*)(ws + (8ull  << 20));        // 6 MB
  unsigned short* wdb   = (unsigned short*)(ws + (14ull << 20));        // 2 MB
  unsigned short* qkvb  = (unsigned short*)(ws + (16ull << 20));        // 24 MB
  unsigned short* vt    = (unsigned short*)(ws + (40ull << 20));        // 8 MB

  cast_all<<<8192, 256, 0, stream>>>(x, w_qkv, w_dense, xb);

  // GEMM1 fused (128x192 tiles -> 512 blocks = 2/CU):
  // rope(q,k) -> qkvb ; v -> vt (transposed)
  gemm_qkv<<<dim3(16, 32), 512, 0, stream>>>(xb, wqkvb, b_qkv, qkvb, vt, fc, fs);
  attn<<<1024, 256, 0, stream>>>(qkvb, vt, xb /* ctx reuse */);
  gemm_out<<<dim3(8, 64), 256, 0, stream>>>(xb, wdb, b_dense, out);
}